// Round 1
// baseline (2499.897 us; speedup 1.0000x reference)
//
#include <hip/hip_runtime.h>
#include <hip/hip_bf16.h>

#define NDIM 256
#define NKD  246
#define KD   10
#define TMAXS 64
#define APAR 1.4f
#define DTS  0.1f

// ---------- build base [256][256] and clipped eigenvalues ----------
__global__ void k_prep(const float* __restrict__ bt, const float* __restrict__ bf,
                       const float* __restrict__ autov, const float* __restrict__ gamma,
                       float* __restrict__ base, float* __restrict__ eig) {
  int r = blockIdx.x, c = threadIdx.x;
  float v = (c < NKD) ? bt[r*NKD + c] : bf[r*KD + (c - NKD)];
  base[r*NDIM + c] = v;
  if (r == 0) {
    float g = gamma[0];
    float xmax = 8.0f*APAR*APAR*g*16.0f - 0.1f;   // sqrt(256)=16
    float e = (c < NKD) ? autov[c] : 0.0f;
    e = fminf(e, xmax);
    e = fmaxf(e, -1e9f);
    eig[c] = e;
  }
}

// ---------- StG = S^T G  (246 x 10), S = base[:,0:246], G = base[:,246:256] ----------
__global__ void k_stg(const float* __restrict__ base, double* __restrict__ StG) {
  int j = blockIdx.x;     // 0..9
  int i = threadIdx.x;    // 0..255
  if (i < NKD) {
    double acc = 0.0;
    for (int r = 0; r < NDIM; ++r)
      acc += (double)base[r*NDIM + i] * (double)base[r*NDIM + NKD + j];
    StG[i*KD + j] = acc;
  }
}

// ---------- R = G - S * StG / 1.3225  (256 x 10) ----------
__global__ void k_R(const float* __restrict__ base, const double* __restrict__ StG,
                    double* __restrict__ Rm) {
  int j = blockIdx.x;     // 0..9
  int r = threadIdx.x;    // 0..255
  double acc = 0.0;
  for (int i = 0; i < NKD; ++i)
    acc += (double)base[r*NDIM + i] * StG[i*KD + j];
  Rm[r*KD + j] = (double)base[r*NDIM + NKD + j] - acc * (1.0/1.3225);
}

// ---------- M10 = R^T G (10x10), then invert it (single thread, fp64 GJ) ----------
__global__ void k_m10(const float* __restrict__ base, const double* __restrict__ Rm,
                      double* __restrict__ M10, double* __restrict__ Mi) {
  int t = threadIdx.x;
  if (t < KD*KD) {
    int j1 = t / KD, j2 = t % KD;
    double acc = 0.0;
    for (int r = 0; r < NDIM; ++r)
      acc += Rm[r*KD + j1] * (double)base[r*NDIM + NKD + j2];
    M10[t] = acc;
  }
  __syncthreads();
  if (t == 0) {
    double M[KD][2*KD];
    for (int i = 0; i < KD; ++i)
      for (int j = 0; j < KD; ++j) { M[i][j] = M10[i*KD + j]; M[i][KD + j] = (i == j) ? 1.0 : 0.0; }
    for (int k = 0; k < KD; ++k) {
      int p = k; double mv = fabs(M[k][k]);
      for (int r = k + 1; r < KD; ++r) { double v = fabs(M[r][k]); if (v > mv) { mv = v; p = r; } }
      if (p != k) for (int c = 0; c < 2*KD; ++c) { double tm = M[k][c]; M[k][c] = M[p][c]; M[p][c] = tm; }
      double pv = M[k][k];
      for (int c = 0; c < 2*KD; ++c) M[k][c] /= pv;
      for (int r = 0; r < KD; ++r) if (r != k) {
        double f = M[r][k];
        for (int c = 0; c < 2*KD; ++c) M[r][c] -= f * M[k][c];
      }
    }
    for (int i = 0; i < KD; ++i)
      for (int j = 0; j < KD; ++j) Mi[i*KD + j] = M[i][KD + j];
  }
}

// ---------- X rows 246..255:  X2 = Mi * R^T ----------
__global__ void k_x2(const double* __restrict__ Mi, const double* __restrict__ Rm,
                     double* __restrict__ X) {
  int j = blockIdx.x;     // 0..9
  int c = threadIdx.x;    // 0..255
  double acc = 0.0;
  for (int l = 0; l < KD; ++l) acc += Mi[j*KD + l] * Rm[c*KD + l];
  X[(NKD + j)*NDIM + c] = acc;
}

// ---------- X rows 0..245:  X1 = (S^T - StG * X2) / 1.3225 ----------
__global__ void k_x1(const float* __restrict__ base, const double* __restrict__ StG,
                     double* __restrict__ X) {
  int c = blockIdx.x;     // column 0..255
  int i = threadIdx.x;    // row 0..255 (only <246 active)
  if (i >= NKD) return;
  double acc = 0.0;
  for (int j = 0; j < KD; ++j) acc += StG[i*KD + j] * X[(NKD + j)*NDIM + c];
  X[i*NDIM + c] = ((double)base[c*NDIM + i] - acc) * (1.0/1.3225);
}

// ---------- Newton-Schulz polish: T = 2I - B*X ; X' = X*T ----------
__global__ void k_T(const float* __restrict__ base, const double* __restrict__ X,
                    double* __restrict__ T) {
  int i = blockIdx.x, j = threadIdx.x;
  double acc = 0.0;
  for (int k = 0; k < NDIM; ++k) acc += (double)base[i*NDIM + k] * X[k*NDIM + j];
  T[i*NDIM + j] = ((i == j) ? 2.0 : 0.0) - acc;
}
__global__ void k_XT(const double* __restrict__ X, const double* __restrict__ T,
                     double* __restrict__ Xo) {
  int i = blockIdx.x, j = threadIdx.x;
  double acc = 0.0;
  for (int k = 0; k < NDIM; ++k) acc += X[i*NDIM + k] * T[k*NDIM + j];
  Xo[i*NDIM + j] = acc;
}

// ---------- At[k][j] = A[j][k],  A = (base*eig) @ X ----------
__global__ void k_At(const float* __restrict__ base, const float* __restrict__ eig,
                     const double* __restrict__ X, float* __restrict__ At) {
  int j = blockIdx.x;     // row of A
  int k = threadIdx.x;    // col of A
  double acc = 0.0;
  for (int m = 0; m < NDIM; ++m)
    acc += (double)base[j*NDIM + m] * (double)eig[m] * X[m*NDIM + k];
  At[k*NDIM + j] = (float)acc;
}

// ---------- the 64-step Euler evolution, rows resident in LDS ----------
__global__ __launch_bounds__(256, 2)
void k_evolve(const float* __restrict__ x_in, const float* __restrict__ At,
              const float* __restrict__ gamma, float* __restrict__ out) {
  __shared__ float xs[32][NDIM];          // 32 KB -> 2 blocks/CU
  const int t = threadIdx.x;
  const int rbase = blockIdx.x * 32;
  #pragma unroll
  for (int i = 0; i < 32; ++i) xs[i][t] = x_in[(rbase + i)*NDIM + t];
  const float g   = fabsf(gamma[0]);
  const float c4g = 4.0f * g;
  const float a2  = APAR * APAR;
  const float lim = 10.0f * APAR;
  const float dtb = DTS * 0.0625f;        // dt * beta, beta = 1/sqrt(256)
  const int r0 = (t >> 5) * 4;            // 8 row-groups of 4
  const int c0 = (t & 31) * 8;            // 32 col-groups of 8

  for (int step = 0; step < TMAXS; ++step) {
    __syncthreads();
    float y[4][8];
    #pragma unroll
    for (int i = 0; i < 4; ++i)
      #pragma unroll
      for (int j = 0; j < 8; ++j) y[i][j] = 0.0f;

    for (int k = 0; k < NDIM; k += 4) {
      float4 xv[4];
      #pragma unroll
      for (int i = 0; i < 4; ++i) xv[i] = *(const float4*)&xs[r0 + i][k];
      #pragma unroll
      for (int kk = 0; kk < 4; ++kk) {
        const float4 a0 = *(const float4*)(At + (k + kk)*NDIM + c0);
        const float4 a1 = *(const float4*)(At + (k + kk)*NDIM + c0 + 4);
        #pragma unroll
        for (int i = 0; i < 4; ++i) {
          const float xf = (kk == 0) ? xv[i].x : (kk == 1) ? xv[i].y : (kk == 2) ? xv[i].z : xv[i].w;
          y[i][0] += xf*a0.x; y[i][1] += xf*a0.y; y[i][2] += xf*a0.z; y[i][3] += xf*a0.w;
          y[i][4] += xf*a1.x; y[i][5] += xf*a1.y; y[i][6] += xf*a1.z; y[i][7] += xf*a1.w;
        }
      }
    }
    __syncthreads();
    #pragma unroll
    for (int i = 0; i < 4; ++i) {
      #pragma unroll
      for (int j = 0; j < 8; ++j) {
        float xc = xs[r0 + i][c0 + j];
        float xn = xc + DTS*(c4g*(a2*xc - xc*xc*xc)) + dtb*y[i][j];
        xn = fminf(fmaxf(xn, -lim), lim);
        xs[r0 + i][c0 + j] = xn;
      }
    }
  }
  __syncthreads();
  #pragma unroll
  for (int i = 0; i < 32; ++i) out[(rbase + i)*NDIM + t] = xs[i][t];
}

extern "C" void kernel_launch(void* const* d_in, const int* in_sizes, int n_in,
                              void* d_out, int out_size, void* d_ws, size_t ws_size,
                              hipStream_t stream) {
  const float* x  = (const float*)d_in[0];
  const float* bt = (const float*)d_in[1];
  const float* bf = (const float*)d_in[2];
  const float* av = (const float*)d_in[3];
  const float* gm = (const float*)d_in[4];
  float* out = (float*)d_out;
  const int Brows = in_sizes[0] / NDIM;   // 16384

  // workspace layout
  float*  base = (float*)d_ws;                    // 65536 f
  float*  eig  = base + NDIM*NDIM;                // 256 f
  float*  At   = eig + NDIM;                      // 65536 f
  double* Xd   = (double*)(At + NDIM*NDIM);       // byte off 525312, 8B aligned
  double* Xe   = Xd + NDIM*NDIM;
  double* Td   = Xe + NDIM*NDIM;
  double* StG  = Td + NDIM*NDIM;                  // 2460 -> pad 2560
  double* Rm   = StG + 2560;                      // 2560
  double* M10  = Rm + 2560;                       // 128
  double* Mi   = M10 + 128;                       // 128

  k_prep<<<NDIM, NDIM, 0, stream>>>(bt, bf, av, gm, base, eig);
  k_stg <<<KD,   NDIM, 0, stream>>>(base, StG);
  k_R   <<<KD,   NDIM, 0, stream>>>(base, StG, Rm);
  k_m10 <<<1,    128,  0, stream>>>(base, Rm, M10, Mi);
  k_x2  <<<KD,   NDIM, 0, stream>>>(Mi, Rm, Xd);
  k_x1  <<<NDIM, NDIM, 0, stream>>>(base, StG, Xd);
  // 3 Newton-Schulz polish iterations (fp64)
  k_T <<<NDIM, NDIM, 0, stream>>>(base, Xd, Td);
  k_XT<<<NDIM, NDIM, 0, stream>>>(Xd, Td, Xe);
  k_T <<<NDIM, NDIM, 0, stream>>>(base, Xe, Td);
  k_XT<<<NDIM, NDIM, 0, stream>>>(Xe, Td, Xd);
  k_T <<<NDIM, NDIM, 0, stream>>>(base, Xd, Td);
  k_XT<<<NDIM, NDIM, 0, stream>>>(Xd, Td, Xe);

  k_At<<<NDIM, NDIM, 0, stream>>>(base, eig, Xe, At);

  k_evolve<<<Brows/32, 256, 0, stream>>>(x, At, gm, out);
}

// Round 2
// 779.157 us; speedup vs baseline: 3.2085x; 3.2085x over previous
//
#include <hip/hip_runtime.h>
#include <hip/hip_bf16.h>

#define NDIM 256
#define NKD  246
#define KD   10
#define TMAXS 64
#define APAR 1.4f
#define DTS  0.1f

typedef _Float16 f16x8 __attribute__((ext_vector_type(8)));
typedef float    f32x4 __attribute__((ext_vector_type(4)));

// ---------- build base [256][256] and clipped eigenvalues ----------
__global__ void k_prep(const float* __restrict__ bt, const float* __restrict__ bf,
                       const float* __restrict__ autov, const float* __restrict__ gamma,
                       float* __restrict__ base, float* __restrict__ eig) {
  int r = blockIdx.x, c = threadIdx.x;
  float v = (c < NKD) ? bt[r*NKD + c] : bf[r*KD + (c - NKD)];
  base[r*NDIM + c] = v;
  if (r == 0) {
    float g = gamma[0];
    float xmax = 8.0f*APAR*APAR*g*16.0f - 0.1f;   // sqrt(256)=16
    float e = (c < NKD) ? autov[c] : 0.0f;
    e = fminf(e, xmax);
    e = fmaxf(e, -1e9f);
    eig[c] = e;
  }
}

// ---------- StG = S^T G  (246 x 10) ----------
__global__ void k_stg(const float* __restrict__ base, double* __restrict__ StG) {
  int j = blockIdx.x, i = threadIdx.x;
  if (i < NKD) {
    double acc = 0.0;
    for (int r = 0; r < NDIM; ++r)
      acc += (double)base[r*NDIM + i] * (double)base[r*NDIM + NKD + j];
    StG[i*KD + j] = acc;
  }
}

// ---------- R = G - S * StG / 1.3225 ----------
__global__ void k_R(const float* __restrict__ base, const double* __restrict__ StG,
                    double* __restrict__ Rm) {
  int j = blockIdx.x, r = threadIdx.x;
  double acc = 0.0;
  for (int i = 0; i < NKD; ++i)
    acc += (double)base[r*NDIM + i] * StG[i*KD + j];
  Rm[r*KD + j] = (double)base[r*NDIM + NKD + j] - acc * (1.0/1.3225);
}

// ---------- M10 = R^T G (10x10) + fp64 GJ inverse ----------
__global__ void k_m10(const float* __restrict__ base, const double* __restrict__ Rm,
                      double* __restrict__ M10, double* __restrict__ Mi) {
  int t = threadIdx.x;
  if (t < KD*KD) {
    int j1 = t / KD, j2 = t % KD;
    double acc = 0.0;
    for (int r = 0; r < NDIM; ++r)
      acc += Rm[r*KD + j1] * (double)base[r*NDIM + NKD + j2];
    M10[t] = acc;
  }
  __syncthreads();
  if (t == 0) {
    double M[KD][2*KD];
    for (int i = 0; i < KD; ++i)
      for (int j = 0; j < KD; ++j) { M[i][j] = M10[i*KD + j]; M[i][KD + j] = (i == j) ? 1.0 : 0.0; }
    for (int k = 0; k < KD; ++k) {
      int p = k; double mv = fabs(M[k][k]);
      for (int r = k + 1; r < KD; ++r) { double v = fabs(M[r][k]); if (v > mv) { mv = v; p = r; } }
      if (p != k) for (int c = 0; c < 2*KD; ++c) { double tm = M[k][c]; M[k][c] = M[p][c]; M[p][c] = tm; }
      double pv = M[k][k];
      for (int c = 0; c < 2*KD; ++c) M[k][c] /= pv;
      for (int r = 0; r < KD; ++r) if (r != k) {
        double f = M[r][k];
        for (int c = 0; c < 2*KD; ++c) M[r][c] -= f * M[k][c];
      }
    }
    for (int i = 0; i < KD; ++i)
      for (int j = 0; j < KD; ++j) Mi[i*KD + j] = M[i][KD + j];
  }
}

// ---------- X rows 246..255:  X2 = Mi * R^T ----------
__global__ void k_x2(const double* __restrict__ Mi, const double* __restrict__ Rm,
                     double* __restrict__ X) {
  int j = blockIdx.x, c = threadIdx.x;
  double acc = 0.0;
  for (int l = 0; l < KD; ++l) acc += Mi[j*KD + l] * Rm[c*KD + l];
  X[(NKD + j)*NDIM + c] = acc;
}

// ---------- X rows 0..245:  X1 = (S^T - StG * X2) / 1.3225 ----------
__global__ void k_x1(const float* __restrict__ base, const double* __restrict__ StG,
                     double* __restrict__ X) {
  int c = blockIdx.x, i = threadIdx.x;
  if (i >= NKD) return;
  double acc = 0.0;
  for (int j = 0; j < KD; ++j) acc += StG[i*KD + j] * X[(NKD + j)*NDIM + c];
  X[i*NDIM + c] = ((double)base[c*NDIM + i] - acc) * (1.0/1.3225);
}

// ---------- Newton-Schulz: T = 2I - B*X ; X' = X*T ----------
__global__ void k_T(const float* __restrict__ base, const double* __restrict__ X,
                    double* __restrict__ T) {
  int i = blockIdx.x, j = threadIdx.x;
  double acc = 0.0;
  for (int k = 0; k < NDIM; ++k) acc += (double)base[i*NDIM + k] * X[k*NDIM + j];
  T[i*NDIM + j] = ((i == j) ? 2.0 : 0.0) - acc;
}
__global__ void k_XT(const double* __restrict__ X, const double* __restrict__ T,
                     double* __restrict__ Xo) {
  int i = blockIdx.x, j = threadIdx.x;
  double acc = 0.0;
  for (int k = 0; k < NDIM; ++k) acc += X[i*NDIM + k] * T[k*NDIM + j];
  Xo[i*NDIM + j] = acc;
}

// ---------- At[k][j] = A[j][k],  A = (base*eig) @ X ----------
__global__ void k_At(const float* __restrict__ base, const float* __restrict__ eig,
                     const double* __restrict__ X, float* __restrict__ At) {
  int j = blockIdx.x;     // row of A
  int k = threadIdx.x;    // col of A
  double acc = 0.0;
  for (int m = 0; m < NDIM; ++m)
    acc += (double)base[j*NDIM + m] * (double)eig[m] * X[m*NDIM + k];
  At[k*NDIM + j] = (float)acc;
}

// ---------- pack At into MFMA B-fragment layout, fp16 hi/lo split ----------
// Bp[kc][g][col][j] = At[kc*32+g*8+j][col]
__global__ void k_pack(const float* __restrict__ At, _Float16* __restrict__ Bh,
                       _Float16* __restrict__ Bl) {
  int col = blockIdx.x, k = threadIdx.x;
  float v = At[k*NDIM + col];
  _Float16 h = (_Float16)v;
  _Float16 lo = (_Float16)(v - (float)h);
  int kc = k >> 5, g = (k >> 3) & 3, j = k & 7;
  int idx = (((kc*4 + g)*NDIM + col) << 3) + j;
  Bh[idx] = h; Bl[idx] = lo;
}

// ---------- 64-step Euler evolution: MFMA fp16-split GEMM, x in registers ----------
__global__ __launch_bounds__(512, 2)
void k_evolve(const float* __restrict__ x_in, const f16x8* __restrict__ Bh,
              const f16x8* __restrict__ Bl, const float* __restrict__ gamma,
              float* __restrict__ out) {
  __shared__ float xsT[NDIM][68];            // x transposed [col][row], padded
  __shared__ f16x8 xhp[4][8][4][16];         // [mt][kc][g][row16] packed A-frags (hi)
  __shared__ f16x8 xlp[4][8][4][16];         // (lo)

  const int t  = threadIdx.x;
  const int w  = t >> 6;                     // wave 0..7
  const int l  = t & 63;
  const int lg = l >> 4;                     // 0..3
  const int lr = l & 15;                     // 0..15
  const int rbase = blockIdx.x * 64;

  const float g   = fabsf(gamma[0]);
  const float c4g = 4.0f * g;
  const float a2  = APAR * APAR;
  const float lim = 10.0f * APAR;
  const float dtb = DTS * 0.0625f;

  // ---- x state in registers, D-layout: xr[mt][nt][r] = x[mt*16+lg*4+r][w*32+nt*16+lr]
  float xr[4][2][4];
  #pragma unroll
  for (int mt = 0; mt < 4; ++mt)
    #pragma unroll
    for (int nt = 0; nt < 2; ++nt) {
      const int col = w*32 + nt*16 + lr;
      #pragma unroll
      for (int r = 0; r < 4; ++r)
        xr[mt][nt][r] = x_in[(rbase + mt*16 + lg*4 + r)*NDIM + col];
    }

  // ---- persistent B fragments (the A matrix) in VGPRs: bh/bl[nt][kc]
  f16x8 bhf[2][8], blf[2][8];
  #pragma unroll
  for (int nt = 0; nt < 2; ++nt) {
    const int col = w*32 + nt*16 + lr;
    #pragma unroll
    for (int kc = 0; kc < 8; ++kc) {
      bhf[nt][kc] = Bh[(kc*4 + lg)*NDIM + col];
      blf[nt][kc] = Bl[(kc*4 + lg)*NDIM + col];
    }
  }

  // ---- helpers ----
  auto writeXS = [&]() {
    #pragma unroll
    for (int mt = 0; mt < 4; ++mt)
      #pragma unroll
      for (int nt = 0; nt < 2; ++nt) {
        const int col = w*32 + nt*16 + lr;
        f32x4 v = { xr[mt][nt][0], xr[mt][nt][1], xr[mt][nt][2], xr[mt][nt][3] };
        *(f32x4*)&xsT[col][mt*16 + lg*4] = v;
      }
  };
  auto convert = [&]() {
    #pragma unroll
    for (int i = 0; i < 4; ++i) {
      const int idx = t + i*512;
      const int row = idx & 63;
      const int kcg = idx >> 6;         // 0..31
      const int kc = kcg >> 2, gg = kcg & 3;
      f16x8 h, lo;
      #pragma unroll
      for (int j = 0; j < 8; ++j) {
        float v = xsT[kc*32 + gg*8 + j][row];
        _Float16 hh = (_Float16)v;
        h[j]  = hh;
        lo[j] = (_Float16)(v - (float)hh);
      }
      xhp[row >> 4][kc][gg][row & 15] = h;
      xlp[row >> 4][kc][gg][row & 15] = lo;
    }
  };

  writeXS();
  __syncthreads();
  convert();
  __syncthreads();

  for (int step = 0; step < TMAXS; ++step) {
    // ---- GEMM: y = x @ At, 4-product fp16 split, acc fp32 ----
    f32x4 acc[4][2] = {};
    #pragma unroll
    for (int kc = 0; kc < 8; ++kc) {
      #pragma unroll
      for (int mt = 0; mt < 4; ++mt) {
        f16x8 ah = xhp[mt][kc][lg][lr];
        f16x8 al = xlp[mt][kc][lg][lr];
        #pragma unroll
        for (int nt = 0; nt < 2; ++nt) {
          acc[mt][nt] = __builtin_amdgcn_mfma_f32_16x16x32_f16(ah, bhf[nt][kc], acc[mt][nt], 0, 0, 0);
          acc[mt][nt] = __builtin_amdgcn_mfma_f32_16x16x32_f16(ah, blf[nt][kc], acc[mt][nt], 0, 0, 0);
          acc[mt][nt] = __builtin_amdgcn_mfma_f32_16x16x32_f16(al, bhf[nt][kc], acc[mt][nt], 0, 0, 0);
          acc[mt][nt] = __builtin_amdgcn_mfma_f32_16x16x32_f16(al, blf[nt][kc], acc[mt][nt], 0, 0, 0);
        }
      }
    }
    // ---- pointwise double-well + Euler + clip, all in registers ----
    #pragma unroll
    for (int mt = 0; mt < 4; ++mt)
      #pragma unroll
      for (int nt = 0; nt < 2; ++nt)
        #pragma unroll
        for (int r = 0; r < 4; ++r) {
          float xc = xr[mt][nt][r];
          float xn = xc + DTS*(c4g*(a2*xc - xc*xc*xc)) + dtb*acc[mt][nt][r];
          xn = fminf(fmaxf(xn, -lim), lim);
          xr[mt][nt][r] = xn;
        }
    writeXS();
    __syncthreads();
    convert();
    __syncthreads();
  }

  // ---- store result ----
  #pragma unroll
  for (int mt = 0; mt < 4; ++mt)
    #pragma unroll
    for (int nt = 0; nt < 2; ++nt) {
      const int col = w*32 + nt*16 + lr;
      #pragma unroll
      for (int r = 0; r < 4; ++r)
        out[(rbase + mt*16 + lg*4 + r)*NDIM + col] = xr[mt][nt][r];
    }
}

extern "C" void kernel_launch(void* const* d_in, const int* in_sizes, int n_in,
                              void* d_out, int out_size, void* d_ws, size_t ws_size,
                              hipStream_t stream) {
  const float* x  = (const float*)d_in[0];
  const float* bt = (const float*)d_in[1];
  const float* bf = (const float*)d_in[2];
  const float* av = (const float*)d_in[3];
  const float* gm = (const float*)d_in[4];
  float* out = (float*)d_out;
  const int Brows = in_sizes[0] / NDIM;   // 16384

  // workspace layout
  float*  base = (float*)d_ws;                    // 65536 f
  float*  eig  = base + NDIM*NDIM;                // 256 f
  float*  At   = eig + NDIM;                      // 65536 f
  double* Xd   = (double*)(At + NDIM*NDIM);       // 16B aligned
  double* Xe   = Xd + NDIM*NDIM;
  double* Td   = Xe + NDIM*NDIM;
  double* StG  = Td + NDIM*NDIM;                  // 2460 -> pad 2560
  double* Rm   = StG + 2560;
  double* M10  = Rm + 2560;
  double* Mi   = M10 + 128;
  // packed fp16 A-fragments overlay Td's space (Td is dead before k_pack runs)
  _Float16* Bph = (_Float16*)Td;                  // 65536 halves = 128KB
  _Float16* Bpl = Bph + NDIM*NDIM;                // 128KB  (Td is 512KB: fits)

  k_prep<<<NDIM, NDIM, 0, stream>>>(bt, bf, av, gm, base, eig);
  k_stg <<<KD,   NDIM, 0, stream>>>(base, StG);
  k_R   <<<KD,   NDIM, 0, stream>>>(base, StG, Rm);
  k_m10 <<<1,    128,  0, stream>>>(base, Rm, M10, Mi);
  k_x2  <<<KD,   NDIM, 0, stream>>>(Mi, Rm, Xd);
  k_x1  <<<NDIM, NDIM, 0, stream>>>(base, StG, Xd);
  // 2 Newton-Schulz polish iterations (fp64) — quadratic: 1e-6 -> 1e-12 -> floor
  k_T <<<NDIM, NDIM, 0, stream>>>(base, Xd, Td);
  k_XT<<<NDIM, NDIM, 0, stream>>>(Xd, Td, Xe);
  k_T <<<NDIM, NDIM, 0, stream>>>(base, Xe, Td);
  k_XT<<<NDIM, NDIM, 0, stream>>>(Xe, Td, Xd);

  k_At  <<<NDIM, NDIM, 0, stream>>>(base, eig, Xd, At);
  k_pack<<<NDIM, NDIM, 0, stream>>>(At, Bph, Bpl);

  k_evolve<<<Brows/64, 512, 0, stream>>>(x, (const f16x8*)Bph, (const f16x8*)Bpl, gm, out);
}

// Round 4
// 443.256 us; speedup vs baseline: 5.6398x; 1.7578x over previous
//
#include <hip/hip_runtime.h>
#include <hip/hip_bf16.h>

#define NDIM 256
#define NKD  246
#define KD   10
#define TMAXS 64
#define APAR 1.4f
#define DTS  0.1f

typedef _Float16 f16x8 __attribute__((ext_vector_type(8)));
typedef float    f32x4 __attribute__((ext_vector_type(4)));

// ---------- build base [256][256] and clipped eigenvalues ----------
__global__ void k_prep(const float* __restrict__ bt, const float* __restrict__ bf,
                       const float* __restrict__ autov, const float* __restrict__ gamma,
                       float* __restrict__ base, float* __restrict__ eig) {
  int r = blockIdx.x, c = threadIdx.x;
  float v = (c < NKD) ? bt[r*NKD + c] : bf[r*KD + (c - NKD)];
  base[r*NDIM + c] = v;
  if (r == 0) {
    float g = gamma[0];
    float xmax = 8.0f*APAR*APAR*g*16.0f - 0.1f;   // sqrt(256)=16
    float e = (c < NKD) ? autov[c] : 0.0f;
    e = fminf(e, xmax);
    e = fmaxf(e, -1e9f);
    eig[c] = e;
  }
}

// ---------- fused: StG col j = S^T G[:,j]; then R[:,j] = G[:,j] - S*StG[:,j]/1.3225 ----------
__global__ void k_stgR(const float* __restrict__ base, double* __restrict__ StG,
                       double* __restrict__ Rm) {
  __shared__ double sg[NKD];
  const int j = blockIdx.x, t = threadIdx.x;
  if (t < NKD) {
    double acc = 0.0;
    for (int r = 0; r < NDIM; ++r)
      acc += (double)base[r*NDIM + t] * (double)base[r*NDIM + NKD + j];
    sg[t] = acc;
    StG[t*KD + j] = acc;
  }
  __syncthreads();
  double acc = 0.0;
  for (int i = 0; i < NKD; ++i)
    acc += (double)base[t*NDIM + i] * sg[i];
  Rm[t*KD + j] = (double)base[t*NDIM + NKD + j] - acc * (1.0/1.3225);
}

// ---------- fused: M10 = R^T G (10x10); parallel fp64 GJ inverse; X2 = Mi*R^T ----------
__global__ void k_m10x2(const float* __restrict__ base, const double* __restrict__ Rm,
                        double* __restrict__ X) {
  __shared__ double M[KD][2*KD];
  __shared__ double fcol[KD];
  __shared__ int piv;
  const int t = threadIdx.x;
  if (t < KD*KD) {
    int j1 = t / KD, j2 = t % KD;
    double acc = 0.0;
    for (int r = 0; r < NDIM; ++r)
      acc += Rm[r*KD + j1] * (double)base[r*NDIM + NKD + j2];
    M[j1][j2] = acc;
    M[j1][KD + j2] = (j1 == j2) ? 1.0 : 0.0;
  }
  __syncthreads();
  for (int k = 0; k < KD; ++k) {
    if (t == 0) {
      int p = k; double mv = fabs(M[k][k]);
      for (int r = k + 1; r < KD; ++r) { double v = fabs(M[r][k]); if (v > mv) { mv = v; p = r; } }
      piv = p;
    }
    __syncthreads();
    int p = piv;
    if (p != k && t < 2*KD) { double tmp = M[k][t]; M[k][t] = M[p][t]; M[p][t] = tmp; }
    __syncthreads();
    double pv = M[k][k];
    __syncthreads();
    if (t < 2*KD) M[k][t] /= pv;
    if (t < KD) fcol[t] = M[t][k];
    __syncthreads();
    if (t < KD*2*KD) {
      int r = t / (2*KD), c = t % (2*KD);
      if (r != k) M[r][c] -= fcol[r] * M[k][c];
    }
    __syncthreads();
  }
  // X2 rows 246..255: X[(246+j)][c] = sum_l Mi[j][l] * Rm[c][l]
  for (int j = 0; j < KD; ++j) {
    double acc = 0.0;
    for (int l = 0; l < KD; ++l) acc += M[j][KD + l] * Rm[t*KD + l];
    X[(NKD + j)*NDIM + t] = acc;
  }
}

// ---------- X rows 0..245:  X1 = (S^T - StG * X2) / 1.3225 ----------
__global__ void k_x1(const float* __restrict__ base, const double* __restrict__ StG,
                     double* __restrict__ X) {
  int c = blockIdx.x, i = threadIdx.x;
  if (i >= NKD) return;
  double acc = 0.0;
  for (int j = 0; j < KD; ++j) acc += StG[i*KD + j] * X[(NKD + j)*NDIM + c];
  X[i*NDIM + c] = ((double)base[c*NDIM + i] - acc) * (1.0/1.3225);
}

// ---------- Newton-Schulz: T = 2I - B*X ; X' = X*T ----------
__global__ void k_T(const float* __restrict__ base, const double* __restrict__ X,
                    double* __restrict__ T) {
  int i = blockIdx.x, j = threadIdx.x;
  double acc = 0.0;
  for (int k = 0; k < NDIM; ++k) acc += (double)base[i*NDIM + k] * X[k*NDIM + j];
  T[i*NDIM + j] = ((i == j) ? 2.0 : 0.0) - acc;
}
__global__ void k_XT(const double* __restrict__ X, const double* __restrict__ T,
                     double* __restrict__ Xo) {
  int i = blockIdx.x, j = threadIdx.x;
  double acc = 0.0;
  for (int k = 0; k < NDIM; ++k) acc += X[i*NDIM + k] * T[k*NDIM + j];
  Xo[i*NDIM + j] = acc;
}

// ---------- fused: row j of A = (base*eig)@X, fp16 hi/lo split, packed B-frag layout ----------
__global__ void k_Atpack(const float* __restrict__ base, const float* __restrict__ eig,
                         const double* __restrict__ X, _Float16* __restrict__ Bh,
                         _Float16* __restrict__ Bl) {
  int j = blockIdx.x;     // row of A  (= column of At)
  int k = threadIdx.x;    // col of A  (= k index of At)
  double acc = 0.0;
  for (int m = 0; m < NDIM; ++m)
    acc += (double)base[j*NDIM + m] * (double)eig[m] * X[m*NDIM + k];
  float v = (float)acc;
  _Float16 h  = (_Float16)v;
  _Float16 lo = (_Float16)(v - (float)h);
  int kc = k >> 5, g = (k >> 3) & 3, jj = k & 7;
  int idx = (((kc*4 + g)*NDIM + j) << 3) + jj;
  Bh[idx] = h; Bl[idx] = lo;
}

// ---------- 64-step Euler evolution: MFMA fp16 3-product split GEMM ----------
__global__ __launch_bounds__(512, 2)
void k_evolve(const float* __restrict__ x_in, const f16x8* __restrict__ Bh,
              const f16x8* __restrict__ Bl, const float* __restrict__ gamma,
              float* __restrict__ out) {
  __shared__ float xsT[NDIM][68];            // x transposed [col][row], padded
  __shared__ f16x8 xhp[4][8][4][16];         // [mt][kc][g][row16] packed A-frags (hi)
  __shared__ f16x8 xlp[4][8][4][16];         // (lo)

  const int t  = threadIdx.x;
  const int w  = t >> 6;                     // wave 0..7
  const int l  = t & 63;
  const int lg = l >> 4;                     // 0..3
  const int lr = l & 15;                     // 0..15
  const int rbase = blockIdx.x * 64;

  const float g   = fabsf(gamma[0]);
  const float c4g = 4.0f * g;
  const float a2  = APAR * APAR;
  const float lim = 10.0f * APAR;
  const float dtb = DTS * 0.0625f;

  // ---- x state in registers, D-layout: xr[mt][nt][r] = x[mt*16+lg*4+r][w*32+nt*16+lr]
  float xr[4][2][4];
  #pragma unroll
  for (int mt = 0; mt < 4; ++mt)
    #pragma unroll
    for (int nt = 0; nt < 2; ++nt) {
      const int col = w*32 + nt*16 + lr;
      #pragma unroll
      for (int r = 0; r < 4; ++r)
        xr[mt][nt][r] = x_in[(rbase + mt*16 + lg*4 + r)*NDIM + col];
    }

  // ---- persistent B fragments (the A matrix) in VGPRs: bh/bl[nt][kc]
  f16x8 bhf[2][8], blf[2][8];
  #pragma unroll
  for (int nt = 0; nt < 2; ++nt) {
    const int col = w*32 + nt*16 + lr;
    #pragma unroll
    for (int kc = 0; kc < 8; ++kc) {
      bhf[nt][kc] = Bh[(kc*4 + lg)*NDIM + col];
      blf[nt][kc] = Bl[(kc*4 + lg)*NDIM + col];
    }
  }

  // ---- helpers ----
  auto writeXS = [&]() {
    #pragma unroll
    for (int mt = 0; mt < 4; ++mt)
      #pragma unroll
      for (int nt = 0; nt < 2; ++nt) {
        const int col = w*32 + nt*16 + lr;
        f32x4 v = { xr[mt][nt][0], xr[mt][nt][1], xr[mt][nt][2], xr[mt][nt][3] };
        *(f32x4*)&xsT[col][mt*16 + lg*4] = v;
      }
  };
  auto convert = [&]() {
    #pragma unroll
    for (int i = 0; i < 4; ++i) {
      const int idx = t + i*512;
      const int row = idx & 63;
      const int kcg = idx >> 6;         // 0..31
      const int kc = kcg >> 2, gg = kcg & 3;
      float vv[8];
      #pragma unroll
      for (int j = 0; j < 8; ++j) vv[j] = xsT[kc*32 + gg*8 + j][row];
      f16x8 h, lo;
      #pragma unroll
      for (int j = 0; j < 4; ++j) {
        auto hp = __builtin_amdgcn_cvt_pkrtz(vv[2*j], vv[2*j+1]);
        h[2*j]   = (_Float16)hp[0];
        h[2*j+1] = (_Float16)hp[1];
        float r0 = vv[2*j]   - (float)hp[0];
        float r1 = vv[2*j+1] - (float)hp[1];
        auto lp = __builtin_amdgcn_cvt_pkrtz(r0, r1);
        lo[2*j]   = (_Float16)lp[0];
        lo[2*j+1] = (_Float16)lp[1];
      }
      xhp[row >> 4][kc][gg][row & 15] = h;
      xlp[row >> 4][kc][gg][row & 15] = lo;
    }
  };

  writeXS();
  __syncthreads();
  convert();
  __syncthreads();

  for (int step = 0; step < TMAXS; ++step) {
    // ---- GEMM: y = x @ At, 3-product fp16 split (hh, hl, lh), acc fp32 ----
    f32x4 acc[4][2] = {};
    #pragma unroll
    for (int kc = 0; kc < 8; ++kc) {
      #pragma unroll
      for (int mt = 0; mt < 4; ++mt) {
        f16x8 ah = xhp[mt][kc][lg][lr];
        f16x8 al = xlp[mt][kc][lg][lr];
        #pragma unroll
        for (int nt = 0; nt < 2; ++nt) {
          acc[mt][nt] = __builtin_amdgcn_mfma_f32_16x16x32_f16(ah, bhf[nt][kc], acc[mt][nt], 0, 0, 0);
          acc[mt][nt] = __builtin_amdgcn_mfma_f32_16x16x32_f16(ah, blf[nt][kc], acc[mt][nt], 0, 0, 0);
          acc[mt][nt] = __builtin_amdgcn_mfma_f32_16x16x32_f16(al, bhf[nt][kc], acc[mt][nt], 0, 0, 0);
        }
      }
    }
    // ---- pointwise double-well + Euler + clip, all in registers ----
    #pragma unroll
    for (int mt = 0; mt < 4; ++mt)
      #pragma unroll
      for (int nt = 0; nt < 2; ++nt)
        #pragma unroll
        for (int r = 0; r < 4; ++r) {
          float xc = xr[mt][nt][r];
          float xn = xc + DTS*(c4g*(a2*xc - xc*xc*xc)) + dtb*acc[mt][nt][r];
          xn = fminf(fmaxf(xn, -lim), lim);
          xr[mt][nt][r] = xn;
        }
    writeXS();
    __syncthreads();
    convert();
    __syncthreads();
  }

  // ---- store result ----
  #pragma unroll
  for (int mt = 0; mt < 4; ++mt)
    #pragma unroll
    for (int nt = 0; nt < 2; ++nt) {
      const int col = w*32 + nt*16 + lr;
      #pragma unroll
      for (int r = 0; r < 4; ++r)
        out[(rbase + mt*16 + lg*4 + r)*NDIM + col] = xr[mt][nt][r];
    }
}

extern "C" void kernel_launch(void* const* d_in, const int* in_sizes, int n_in,
                              void* d_out, int out_size, void* d_ws, size_t ws_size,
                              hipStream_t stream) {
  const float* x  = (const float*)d_in[0];
  const float* bt = (const float*)d_in[1];
  const float* bf = (const float*)d_in[2];
  const float* av = (const float*)d_in[3];
  const float* gm = (const float*)d_in[4];
  float* out = (float*)d_out;
  const int Brows = in_sizes[0] / NDIM;   // 16384

  // workspace layout
  float*  base = (float*)d_ws;                    // 65536 f
  float*  eig  = base + NDIM*NDIM;                // 256 f (offset 262144 B)
  double* Xd   = (double*)(eig + NDIM);           // offset 263168 B, 8B aligned
  double* Xe   = Xd + NDIM*NDIM;
  double* Td   = Xe + NDIM*NDIM;
  double* StG  = Td + NDIM*NDIM;                  // 2460 -> pad 2560
  double* Rm   = StG + 2560;                      // 2560
  _Float16* Bph = (_Float16*)(Rm + 2560);         // 65536 halves = 128 KB
  _Float16* Bpl = Bph + NDIM*NDIM;                // 128 KB

  k_prep <<<NDIM, NDIM, 0, stream>>>(bt, bf, av, gm, base, eig);
  k_stgR <<<KD,   NDIM, 0, stream>>>(base, StG, Rm);
  k_m10x2<<<1,    NDIM, 0, stream>>>(base, Rm, Xd);
  k_x1   <<<NDIM, NDIM, 0, stream>>>(base, StG, Xd);
  // 1 Newton-Schulz polish iteration (fp64): 1e-6 -> 1e-12
  k_T <<<NDIM, NDIM, 0, stream>>>(base, Xd, Td);
  k_XT<<<NDIM, NDIM, 0, stream>>>(Xd, Td, Xe);

  k_Atpack<<<NDIM, NDIM, 0, stream>>>(base, eig, Xe, Bph, Bpl);

  k_evolve<<<Brows/64, 512, 0, stream>>>(x, (const f16x8*)Bph, (const f16x8*)Bpl, gm, out);
}

// Round 5
// 419.988 us; speedup vs baseline: 5.9523x; 1.0554x over previous
//
#include <hip/hip_runtime.h>
#include <hip/hip_bf16.h>

#define NDIM 256
#define NKD  246
#define KD   10
#define TMAXS 64
#define APAR 1.4f
#define DTS  0.1f

typedef _Float16 f16x8 __attribute__((ext_vector_type(8)));
typedef float    f32x4 __attribute__((ext_vector_type(4)));

// ---------- build base [256][256] and clipped eigenvalues ----------
__global__ void k_prep(const float* __restrict__ bt, const float* __restrict__ bf,
                       const float* __restrict__ autov, const float* __restrict__ gamma,
                       float* __restrict__ base, float* __restrict__ eig) {
  int r = blockIdx.x, c = threadIdx.x;
  float v = (c < NKD) ? bt[r*NKD + c] : bf[r*KD + (c - NKD)];
  base[r*NDIM + c] = v;
  if (r == 0) {
    float g = gamma[0];
    float xmax = 8.0f*APAR*APAR*g*16.0f - 0.1f;   // sqrt(256)=16
    float e = (c < NKD) ? autov[c] : 0.0f;
    e = fminf(e, xmax);
    e = fmaxf(e, -1e9f);
    eig[c] = e;
  }
}

// ---------- fused: StG col j = S^T G[:,j]; then R[:,j] = G[:,j] - S*StG[:,j]/1.3225 ----------
__global__ void k_stgR(const float* __restrict__ base, double* __restrict__ StG,
                       double* __restrict__ Rm) {
  __shared__ double sg[NKD];
  const int j = blockIdx.x, t = threadIdx.x;
  if (t < NKD) {
    double acc = 0.0;
    for (int r = 0; r < NDIM; ++r)
      acc += (double)base[r*NDIM + t] * (double)base[r*NDIM + NKD + j];
    sg[t] = acc;
    StG[t*KD + j] = acc;
  }
  __syncthreads();
  double acc = 0.0;
  for (int i = 0; i < NKD; ++i)
    acc += (double)base[t*NDIM + i] * sg[i];
  Rm[t*KD + j] = (double)base[t*NDIM + NKD + j] - acc * (1.0/1.3225);
}

// ---------- fused: M10 = R^T G (10x10); parallel fp64 GJ inverse; X2 = Mi*R^T ----------
__global__ void k_m10x2(const float* __restrict__ base, const double* __restrict__ Rm,
                        double* __restrict__ X) {
  __shared__ double M[KD][2*KD];
  __shared__ double fcol[KD];
  __shared__ int piv;
  const int t = threadIdx.x;
  if (t < KD*KD) {
    int j1 = t / KD, j2 = t % KD;
    double acc = 0.0;
    for (int r = 0; r < NDIM; ++r)
      acc += Rm[r*KD + j1] * (double)base[r*NDIM + NKD + j2];
    M[j1][j2] = acc;
    M[j1][KD + j2] = (j1 == j2) ? 1.0 : 0.0;
  }
  __syncthreads();
  for (int k = 0; k < KD; ++k) {
    if (t == 0) {
      int p = k; double mv = fabs(M[k][k]);
      for (int r = k + 1; r < KD; ++r) { double v = fabs(M[r][k]); if (v > mv) { mv = v; p = r; } }
      piv = p;
    }
    __syncthreads();
    int p = piv;
    if (p != k && t < 2*KD) { double tmp = M[k][t]; M[k][t] = M[p][t]; M[p][t] = tmp; }
    __syncthreads();
    double pv = M[k][k];
    __syncthreads();
    if (t < 2*KD) M[k][t] /= pv;
    if (t < KD) fcol[t] = M[t][k];
    __syncthreads();
    if (t < KD*2*KD) {
      int r = t / (2*KD), c = t % (2*KD);
      if (r != k) M[r][c] -= fcol[r] * M[k][c];
    }
    __syncthreads();
  }
  for (int j = 0; j < KD; ++j) {
    double acc = 0.0;
    for (int l = 0; l < KD; ++l) acc += M[j][KD + l] * Rm[t*KD + l];
    X[(NKD + j)*NDIM + t] = acc;
  }
}

// ---------- X rows 0..245:  X1 = (S^T - StG * X2) / 1.3225 ----------
__global__ void k_x1(const float* __restrict__ base, const double* __restrict__ StG,
                     double* __restrict__ X) {
  int c = blockIdx.x, i = threadIdx.x;
  if (i >= NKD) return;
  double acc = 0.0;
  for (int j = 0; j < KD; ++j) acc += StG[i*KD + j] * X[(NKD + j)*NDIM + c];
  X[i*NDIM + c] = ((double)base[c*NDIM + i] - acc) * (1.0/1.3225);
}

// ---------- Newton-Schulz: T = 2I - B*X ; X' = X*T ----------
__global__ void k_T(const float* __restrict__ base, const double* __restrict__ X,
                    double* __restrict__ T) {
  int i = blockIdx.x, j = threadIdx.x;
  double acc = 0.0;
  for (int k = 0; k < NDIM; ++k) acc += (double)base[i*NDIM + k] * X[k*NDIM + j];
  T[i*NDIM + j] = ((i == j) ? 2.0 : 0.0) - acc;
}
__global__ void k_XT(const double* __restrict__ X, const double* __restrict__ T,
                     double* __restrict__ Xo) {
  int i = blockIdx.x, j = threadIdx.x;
  double acc = 0.0;
  for (int k = 0; k < NDIM; ++k) acc += X[i*NDIM + k] * T[k*NDIM + j];
  Xo[i*NDIM + j] = acc;
}

// ---------- fused: A[m][k] = (base*eig)@X, fp16 hi/lo split, A-operand frag layout ----------
// frag index: Af[((kc*256 + m)*4 + lg)] is f16x8 with elems j: A[m][kc*32+lg*8+j]
__global__ void k_Afrag(const float* __restrict__ base, const float* __restrict__ eig,
                        const double* __restrict__ X, _Float16* __restrict__ Ah,
                        _Float16* __restrict__ Al) {
  int m = blockIdx.x;     // row of A (out feature)
  int k = threadIdx.x;    // col of A (in feature)
  double acc = 0.0;
  for (int q = 0; q < NDIM; ++q)
    acc += (double)base[m*NDIM + q] * (double)eig[q] * X[q*NDIM + k];
  float v = (float)acc;
  _Float16 h  = (_Float16)v;
  _Float16 lo = (_Float16)(v - (float)h);
  int kc = k >> 5, lg = (k >> 3) & 3, jj = k & 7;
  int idx = (((kc*NDIM + m)*4 + lg) << 3) + jj;
  Ah[idx] = h; Al[idx] = lo;
}

// ---------- 64-step Euler evolution: Y^T = A x^T, A persistent in VGPRs ----------
// wave w owns out-features m in [32w, 32w+32); D-layout of its output IS the
// kc=w slice of next step's B-fragments (intra-lane repack, one barrier/step).
__global__ __launch_bounds__(512, 2)
void k_evolve(const float* __restrict__ x_in, const f16x8* __restrict__ Ah,
              const f16x8* __restrict__ Al, const float* __restrict__ gamma,
              float* __restrict__ out) {
  __shared__ f16x8 zh[2][8][4][64];   // [buf][kc][nt][lane]  x^T hi frags, 64 KB
  __shared__ f16x8 zl[2][8][4][64];   // lo frags, 64 KB

  const int t  = threadIdx.x;
  const int w  = t >> 6;              // wave 0..7 -> out-feature slice & kc slice
  const int l  = t & 63;
  const int lg = l >> 4;              // 0..3
  const int lr = l & 15;              // 0..15
  const int rbase = blockIdx.x * 64;

  const float g   = fabsf(gamma[0]);
  const float c4g = 4.0f * g;
  const float a2  = APAR * APAR;
  const float lim = 10.0f * APAR;
  const float dtb = DTS * 0.0625f;    // dt * beta

  // ---- persistent A-operand fragments (hi/lo): ahf[mt][kc], m = w*32+mt*16+lr
  f16x8 ahf[2][8], alf[2][8];
  #pragma unroll
  for (int mt = 0; mt < 2; ++mt) {
    const int m = w*32 + mt*16 + lr;
    #pragma unroll
    for (int kc = 0; kc < 8; ++kc) {
      ahf[mt][kc] = Ah[(kc*NDIM + m)*4 + lg];
      alf[mt][kc] = Al[(kc*NDIM + m)*4 + lg];
    }
  }

  // ---- x state in D-layout: xr[mt][nt][reg] = x[r = nt*16+lr][c = w*32+mt*16+lg*4+reg]
  f32x4 xr[2][4];
  #pragma unroll
  for (int mt = 0; mt < 2; ++mt)
    #pragma unroll
    for (int nt = 0; nt < 4; ++nt) {
      const int row = rbase + nt*16 + lr;
      const int col = w*32 + mt*16 + lg*4;
      xr[mt][nt] = *(const f32x4*)&x_in[row*NDIM + col];
    }

  const int lp   = (lg >> 1)*16 + lr;   // partial target lane (add 2*mt*16)
  const int boff = (lg & 1)*8;          // byte offset of j-quad within frag elem

  // ---- emit: split xr to fp16 h/l and scatter into B-frag slice kc=w of buffer b
  auto emit = [&](int b) {
    #pragma unroll
    for (int mt = 0; mt < 2; ++mt) {
      const int tl = mt*32 + lp;        // target lane l'
      #pragma unroll
      for (int nt = 0; nt < 4; ++nt) {
        f32x4 v = xr[mt][nt];
        auto h01 = __builtin_amdgcn_cvt_pkrtz(v[0], v[1]);
        auto h23 = __builtin_amdgcn_cvt_pkrtz(v[2], v[3]);
        float r0 = v[0] - (float)h01[0];
        float r1 = v[1] - (float)h01[1];
        float r2 = v[2] - (float)h23[0];
        float r3 = v[3] - (float)h23[1];
        auto l01 = __builtin_amdgcn_cvt_pkrtz(r0, r1);
        auto l23 = __builtin_amdgcn_cvt_pkrtz(r2, r3);
        uint2 uh, ul;
        __builtin_memcpy(&uh.x, &h01, 4);
        __builtin_memcpy(&uh.y, &h23, 4);
        __builtin_memcpy(&ul.x, &l01, 4);
        __builtin_memcpy(&ul.y, &l23, 4);
        *(uint2*)((char*)&zh[b][w][nt][tl] + boff) = uh;
        *(uint2*)((char*)&zl[b][w][nt][tl] + boff) = ul;
      }
    }
  };

  emit(0);
  __syncthreads();

  for (int step = 0; step < TMAXS; ++step) {
    const int rb = step & 1, wb = rb ^ 1;
    // ---- GEMM: Y^T = A x^T, 3-product fp16 split (Ah*zh + Ah*zl + Al*zh) ----
    f32x4 acc[2][4] = {};
    #pragma unroll
    for (int kc = 0; kc < 8; ++kc) {
      f16x8 bh[4], bl[4];
      #pragma unroll
      for (int nt = 0; nt < 4; ++nt) {
        bh[nt] = zh[rb][kc][nt][l];
        bl[nt] = zl[rb][kc][nt][l];
      }
      #pragma unroll
      for (int mt = 0; mt < 2; ++mt)
        #pragma unroll
        for (int nt = 0; nt < 4; ++nt) {
          acc[mt][nt] = __builtin_amdgcn_mfma_f32_16x16x32_f16(ahf[mt][kc], bh[nt], acc[mt][nt], 0, 0, 0);
          acc[mt][nt] = __builtin_amdgcn_mfma_f32_16x16x32_f16(ahf[mt][kc], bl[nt], acc[mt][nt], 0, 0, 0);
          acc[mt][nt] = __builtin_amdgcn_mfma_f32_16x16x32_f16(alf[mt][kc], bh[nt], acc[mt][nt], 0, 0, 0);
        }
    }
    // ---- pointwise double-well + Euler + clip, in registers ----
    #pragma unroll
    for (int mt = 0; mt < 2; ++mt)
      #pragma unroll
      for (int nt = 0; nt < 4; ++nt)
        #pragma unroll
        for (int r = 0; r < 4; ++r) {
          float xc = xr[mt][nt][r];
          float xn = xc + DTS*(c4g*(a2*xc - xc*xc*xc)) + dtb*acc[mt][nt][r];
          xn = fminf(fmaxf(xn, -lim), lim);
          xr[mt][nt][r] = xn;
        }
    emit(wb);
    __syncthreads();
  }

  // ---- store result ----
  #pragma unroll
  for (int mt = 0; mt < 2; ++mt)
    #pragma unroll
    for (int nt = 0; nt < 4; ++nt) {
      const int row = rbase + nt*16 + lr;
      const int col = w*32 + mt*16 + lg*4;
      *(f32x4*)&out[row*NDIM + col] = xr[mt][nt];
    }
}

extern "C" void kernel_launch(void* const* d_in, const int* in_sizes, int n_in,
                              void* d_out, int out_size, void* d_ws, size_t ws_size,
                              hipStream_t stream) {
  const float* x  = (const float*)d_in[0];
  const float* bt = (const float*)d_in[1];
  const float* bf = (const float*)d_in[2];
  const float* av = (const float*)d_in[3];
  const float* gm = (const float*)d_in[4];
  float* out = (float*)d_out;
  const int Brows = in_sizes[0] / NDIM;   // 16384

  // workspace layout
  float*  base = (float*)d_ws;                    // 65536 f
  float*  eig  = base + NDIM*NDIM;                // 256 f
  double* Xd   = (double*)(eig + NDIM);           // 8B aligned
  double* Xe   = Xd + NDIM*NDIM;
  double* Td   = Xe + NDIM*NDIM;
  double* StG  = Td + NDIM*NDIM;                  // 2460 -> pad 2560
  double* Rm   = StG + 2560;
  _Float16* Aph = (_Float16*)(Rm + 2560);         // 65536 halves = 128 KB
  _Float16* Apl = Aph + NDIM*NDIM;                // 128 KB

  k_prep <<<NDIM, NDIM, 0, stream>>>(bt, bf, av, gm, base, eig);
  k_stgR <<<KD,   NDIM, 0, stream>>>(base, StG, Rm);
  k_m10x2<<<1,    NDIM, 0, stream>>>(base, Rm, Xd);
  k_x1   <<<NDIM, NDIM, 0, stream>>>(base, StG, Xd);
  // 1 Newton-Schulz polish iteration (fp64): 1e-6 -> 1e-12
  k_T <<<NDIM, NDIM, 0, stream>>>(base, Xd, Td);
  k_XT<<<NDIM, NDIM, 0, stream>>>(Xd, Td, Xe);

  k_Afrag<<<NDIM, NDIM, 0, stream>>>(base, eig, Xe, Aph, Apl);

  k_evolve<<<Brows/64, 512, 0, stream>>>(x, (const f16x8*)Aph, (const f16x8*)Apl, gm, out);
}